// Round 1
// baseline (261.461 us; speedup 1.0000x reference)
//
#include <hip/hip_runtime.h>

// Shapes (fixed): x (32,12,256,256) f32, weight (256,12,1,1) f32, bias (256) f32
// Outputs: t (32,12,128,128) then out (32,256,128,128), concatenated in d_out.

#define T_ELEMS 6291456      // 32*12*128*128
#define HW_T    16384        // 128*128
#define HW_X    65536        // 256*256

// Kernel 1: fused iwt(up2) -> blur(down2) -> dwt(down2) as one separable
// stride-2 4x4-tap filter bank. F[analysis][synthesis][tap], scale 1/16/dim.
__global__ __launch_bounds__(256) void wavelet_t_kernel(
    const float* __restrict__ x, float* __restrict__ t)
{
    const int v  = threadIdx.x;                  // 0..127
    const int u  = blockIdx.x * 2 + threadIdx.y; // 0..127
    const int ch = blockIdx.y;                   // 0..2
    const int b  = blockIdx.z;                   // 0..31

    const float F[2][2][4] = {
        { { 1.f,  7.f,  7.f,  1.f}, {-1.f, -1.f, 1.f,  1.f} },  // analysis L
        { { 1.f,  5.f, -5.f, -1.f}, {-1.f,  1.f, 1.f, -1.f} }   // analysis H
    };

    float acc[4] = {0.f, 0.f, 0.f, 0.f};   // k = kr + 2*kc : ll, lh, hl, hh

    const int r0 = 2 * u - 1;
    const int c0 = 2 * v - 1;

    #pragma unroll
    for (int g = 0; g < 4; ++g) {            // input groups: ll,-lh,-hl,hh
        const int gr = g & 1, gc = g >> 1;   // synthesis row/col type
        const float* xp = x + ((size_t)(b * 12 + g * 3 + ch)) * HW_X;
        float cf0[4], cf1[4];
        #pragma unroll
        for (int dy = 0; dy < 4; ++dy) {
            const int r = r0 + dy;
            float row[4];
            if (r >= 0 && r < 256) {
                const float* rp = xp + (r << 8);
                #pragma unroll
                for (int dx = 0; dx < 4; ++dx) {
                    const int c = c0 + dx;
                    row[dx] = (c >= 0 && c < 256) ? rp[c] : 0.f;
                }
            } else {
                row[0] = row[1] = row[2] = row[3] = 0.f;
            }
            float s0 = 0.f, s1 = 0.f;
            #pragma unroll
            for (int dx = 0; dx < 4; ++dx) {
                s0 = fmaf(F[0][gc][dx], row[dx], s0);
                s1 = fmaf(F[1][gc][dx], row[dx], s1);
            }
            cf0[dy] = s0; cf1[dy] = s1;
        }
        #pragma unroll
        for (int dy = 0; dy < 4; ++dy) {
            acc[0] = fmaf(F[0][gr][dy], cf0[dy], acc[0]);
            acc[1] = fmaf(F[1][gr][dy], cf0[dy], acc[1]);
            acc[2] = fmaf(F[0][gr][dy], cf1[dy], acc[2]);
            acc[3] = fmaf(F[1][gr][dy], cf1[dy], acc[3]);
        }
    }

    const float sc = 1.f / 256.f;
    #pragma unroll
    for (int k = 0; k < 4; ++k) {
        t[((size_t)(b * 12 + k * 3 + ch)) * HW_T + (u << 7) + v] = acc[k] * sc;
    }
}

// Kernel 2: out[b,o,h,w] = lrelu( sum_c t[b,c,h,w] * w[o,c]/sqrt(12) + bias[o] ) * sqrt(2)
// Each block: 64 output channels (blockIdx.z), 1024 spatial positions, float4 per thread.
__global__ __launch_bounds__(256) void conv1x1_kernel(
    const float* __restrict__ t, const float* __restrict__ w,
    const float* __restrict__ bias, float* __restrict__ out)
{
    __shared__ float ws[64 * 12];
    __shared__ float bs[64];
    const int tid = threadIdx.x;
    const int b   = blockIdx.y;
    const int oz  = blockIdx.z;    // 0..3 -> 64 output channels each

    const float scale = 0.2886751345948129f;  // 1/sqrt(12)
    for (int i = tid; i < 768; i += 256) ws[i] = w[oz * 768 + i] * scale;
    if (tid < 64) bs[tid] = bias[oz * 64 + tid];
    __syncthreads();

    const int base = blockIdx.x * 1024 + tid * 4;

    float4 tv[12];
    #pragma unroll
    for (int c = 0; c < 12; ++c)
        tv[c] = *reinterpret_cast<const float4*>(t + ((size_t)(b * 12 + c)) * HW_T + base);

    const float SQ2 = 1.4142135623730951f;
    for (int oo = 0; oo < 64; ++oo) {
        const float bo = bs[oo];
        float4 a = make_float4(bo, bo, bo, bo);
        #pragma unroll
        for (int c = 0; c < 12; ++c) {
            const float wv = ws[oo * 12 + c];
            a.x = fmaf(tv[c].x, wv, a.x);
            a.y = fmaf(tv[c].y, wv, a.y);
            a.z = fmaf(tv[c].z, wv, a.z);
            a.w = fmaf(tv[c].w, wv, a.w);
        }
        a.x = fmaxf(a.x, 0.2f * a.x) * SQ2;
        a.y = fmaxf(a.y, 0.2f * a.y) * SQ2;
        a.z = fmaxf(a.z, 0.2f * a.z) * SQ2;
        a.w = fmaxf(a.w, 0.2f * a.w) * SQ2;
        const int o = oz * 64 + oo;
        *reinterpret_cast<float4*>(out + ((size_t)(b * 256 + o)) * HW_T + base) = a;
    }
}

extern "C" void kernel_launch(void* const* d_in, const int* in_sizes, int n_in,
                              void* d_out, int out_size, void* d_ws, size_t ws_size,
                              hipStream_t stream) {
    const float* x    = (const float*)d_in[0];
    const float* wgt  = (const float*)d_in[1];
    const float* bias = (const float*)d_in[2];
    float* t   = (float*)d_out;
    float* out = t + T_ELEMS;

    dim3 b1(128, 2, 1), g1(64, 3, 32);
    hipLaunchKernelGGL(wavelet_t_kernel, g1, b1, 0, stream, x, t);

    dim3 b2(256, 1, 1), g2(16, 32, 4);
    hipLaunchKernelGGL(conv1x1_kernel, g2, b2, 0, stream, t, wgt, bias, out);
}

// Round 2
// 153.251 us; speedup vs baseline: 1.7061x; 1.7061x over previous
//
#include <hip/hip_runtime.h>

// Shapes (fixed): x (32,12,256,256) f32, weight (256,12,1,1) f32, bias (256) f32
// Outputs: t (32,12,128,128) then out (32,256,128,128), concatenated in d_out.

#define T_ELEMS 6291456      // 32*12*128*128
#define HW_T    16384        // 128*128
#define HW_X    65536        // 256*256

typedef float f4v __attribute__((ext_vector_type(4)));

// Kernel 1: fused iwt(up2) -> blur(down2) -> dwt(down2) as one separable
// stride-2 4x4-tap filter bank. Each thread computes 4 consecutive-in-v
// output pixels so global loads are float4 (coalesced), plus 2 predicated
// edge scalars per row.
__global__ __launch_bounds__(256) void wavelet_t_kernel(
    const float* __restrict__ x, float* __restrict__ t)
{
    const int tid = threadIdx.x;
    const int q   = tid & 31;                 // v = 4q .. 4q+3
    const int ur  = tid >> 5;                 // 0..7
    const int u   = blockIdx.x * 8 + ur;      // 0..127
    const int ch  = blockIdx.y;               // 0..2
    const int b   = blockIdx.z;               // 0..31

    const float F[2][2][4] = {
        { { 1.f,  7.f,  7.f,  1.f}, {-1.f, -1.f, 1.f,  1.f} },  // analysis L
        { { 1.f,  5.f, -5.f, -1.f}, {-1.f,  1.f, 1.f, -1.f} }   // analysis H
    };

    float acc[4][4];                           // [kind ll,lh,hl,hh][px]
    #pragma unroll
    for (int k = 0; k < 4; ++k)
        #pragma unroll
        for (int p = 0; p < 4; ++p) acc[k][p] = 0.f;

    const int r0    = 2 * u - 1;
    const int cbase = 8 * q;                   // need cols cbase-1 .. cbase+8

    #pragma unroll
    for (int g = 0; g < 4; ++g) {              // input groups: ll,-lh,-hl,hh
        const int gr = g & 1, gc = g >> 1;
        const float* xp = x + ((size_t)(b * 12 + g * 3 + ch)) * HW_X;
        #pragma unroll
        for (int dy = 0; dy < 4; ++dy) {
            const int r = r0 + dy;
            float c[10];
            if (r >= 0 && r < 256) {
                const float* rp = xp + (r << 8) + cbase;
                const float4 A = *reinterpret_cast<const float4*>(rp);
                const float4 B = *reinterpret_cast<const float4*>(rp + 4);
                c[1] = A.x; c[2] = A.y; c[3] = A.z; c[4] = A.w;
                c[5] = B.x; c[6] = B.y; c[7] = B.z; c[8] = B.w;
                float left = 0.f, right = 0.f;
                if (q > 0)  left  = rp[-1];
                if (q < 31) right = rp[8];
                c[0] = left; c[9] = right;
            } else {
                #pragma unroll
                for (int i = 0; i < 10; ++i) c[i] = 0.f;
            }
            #pragma unroll
            for (int p = 0; p < 4; ++p) {
                float s0 = 0.f, s1 = 0.f;
                #pragma unroll
                for (int dx = 0; dx < 4; ++dx) {
                    s0 = fmaf(F[0][gc][dx], c[2 * p + dx], s0);
                    s1 = fmaf(F[1][gc][dx], c[2 * p + dx], s1);
                }
                acc[0][p] = fmaf(F[0][gr][dy], s0, acc[0][p]);
                acc[1][p] = fmaf(F[1][gr][dy], s0, acc[1][p]);
                acc[2][p] = fmaf(F[0][gr][dy], s1, acc[2][p]);
                acc[3][p] = fmaf(F[1][gr][dy], s1, acc[3][p]);
            }
        }
    }

    const float sc = 1.f / 256.f;
    #pragma unroll
    for (int k = 0; k < 4; ++k) {
        float4 o;
        o.x = acc[k][0] * sc; o.y = acc[k][1] * sc;
        o.z = acc[k][2] * sc; o.w = acc[k][3] * sc;
        *reinterpret_cast<float4*>(
            t + ((size_t)(b * 12 + k * 3 + ch)) * HW_T + (u << 7) + 4 * q) = o;
    }
}

// Kernel 2: out[b,o,h,w] = lrelu( sum_c t[b,c,h,w] * w[o,c]/sqrt(12) + bias[o] ) * sqrt(2)
// 128 output channels per block; t read once per 128 channels; non-temporal
// stores (out is never re-read -> keep L2 for t).
__global__ __launch_bounds__(256) void conv1x1_kernel(
    const float* __restrict__ t, const float* __restrict__ w,
    const float* __restrict__ bias, float* __restrict__ out)
{
    __shared__ float ws[128 * 12];
    __shared__ float bs[128];
    const int tid = threadIdx.x;
    const int b   = blockIdx.y;
    const int oz  = blockIdx.z;                // 0..1 -> 128 out channels each

    const float scale = 0.2886751345948129f;   // 1/sqrt(12)
    for (int i = tid; i < 1536; i += 256) ws[i] = w[oz * 1536 + i] * scale;
    if (tid < 128) bs[tid] = bias[oz * 128 + tid];
    __syncthreads();

    const int base = blockIdx.x * 1024 + tid * 4;

    float4 tv[12];
    #pragma unroll
    for (int c = 0; c < 12; ++c)
        tv[c] = *reinterpret_cast<const float4*>(t + ((size_t)(b * 12 + c)) * HW_T + base);

    const float SQ2 = 1.4142135623730951f;
    float* outp = out + ((size_t)(b * 256 + oz * 128)) * HW_T + base;

    #pragma unroll 4
    for (int oo = 0; oo < 128; ++oo) {
        const float4 w0 = *reinterpret_cast<const float4*>(&ws[oo * 12 + 0]);
        const float4 w1 = *reinterpret_cast<const float4*>(&ws[oo * 12 + 4]);
        const float4 w2 = *reinterpret_cast<const float4*>(&ws[oo * 12 + 8]);
        const float bo = bs[oo];
        float4 a = make_float4(bo, bo, bo, bo);
        #pragma unroll
        for (int c = 0; c < 4; ++c) {
            const float wv = (&w0.x)[c];
            a.x = fmaf(tv[c].x, wv, a.x); a.y = fmaf(tv[c].y, wv, a.y);
            a.z = fmaf(tv[c].z, wv, a.z); a.w = fmaf(tv[c].w, wv, a.w);
        }
        #pragma unroll
        for (int c = 0; c < 4; ++c) {
            const float wv = (&w1.x)[c];
            a.x = fmaf(tv[c + 4].x, wv, a.x); a.y = fmaf(tv[c + 4].y, wv, a.y);
            a.z = fmaf(tv[c + 4].z, wv, a.z); a.w = fmaf(tv[c + 4].w, wv, a.w);
        }
        #pragma unroll
        for (int c = 0; c < 4; ++c) {
            const float wv = (&w2.x)[c];
            a.x = fmaf(tv[c + 8].x, wv, a.x); a.y = fmaf(tv[c + 8].y, wv, a.y);
            a.z = fmaf(tv[c + 8].z, wv, a.z); a.w = fmaf(tv[c + 8].w, wv, a.w);
        }
        a.x = fmaxf(a.x, 0.2f * a.x) * SQ2;
        a.y = fmaxf(a.y, 0.2f * a.y) * SQ2;
        a.z = fmaxf(a.z, 0.2f * a.z) * SQ2;
        a.w = fmaxf(a.w, 0.2f * a.w) * SQ2;

        f4v av = { a.x, a.y, a.z, a.w };
        __builtin_nontemporal_store(
            av, reinterpret_cast<f4v*>(outp + (size_t)oo * HW_T));
    }
}

extern "C" void kernel_launch(void* const* d_in, const int* in_sizes, int n_in,
                              void* d_out, int out_size, void* d_ws, size_t ws_size,
                              hipStream_t stream) {
    const float* x    = (const float*)d_in[0];
    const float* wgt  = (const float*)d_in[1];
    const float* bias = (const float*)d_in[2];
    float* t   = (float*)d_out;
    float* out = t + T_ELEMS;

    dim3 b1(256, 1, 1), g1(16, 3, 32);
    hipLaunchKernelGGL(wavelet_t_kernel, g1, b1, 0, stream, x, t);

    dim3 b2(256, 1, 1), g2(16, 32, 2);
    hipLaunchKernelGGL(conv1x1_kernel, g2, b2, 0, stream, t, wgt, bias, out);
}

// Round 3
// 132.723 us; speedup vs baseline: 1.9700x; 1.1547x over previous
//
#include <hip/hip_runtime.h>

// Shapes (fixed): x (32,12,256,256) f32, weight (256,12,1,1) f32, bias (256) f32
// Outputs: t (32,12,128,128) then out (32,256,128,128), concatenated in d_out.

#define T_ELEMS 6291456      // 32*12*128*128
#define HW_T    16384        // 128*128
#define HW_X    65536        // 256*256

typedef float f4v __attribute__((ext_vector_type(4)));

// Fully fused: iwt(up2)->blur(down2)->dwt(down2) as one separable stride-2
// 4x4-tap filter bank (t kept in registers, nt-stored), then 12->256 1x1
// conv + bias + lrelu*sqrt2 directly from registers.
// Block = 256 threads = 8 u-rows x (128 v / 4 px per thread). Grid (16, 32).
__global__ __launch_bounds__(256) void fused_fromrgb_kernel(
    const float* __restrict__ x, const float* __restrict__ w,
    const float* __restrict__ bias, float* __restrict__ t,
    float* __restrict__ out)
{
    __shared__ float ws[256 * 12];
    __shared__ float bs[256];
    const int tid = threadIdx.x;

    // Stage weights (overlaps with phase 1; sync deferred until conv).
    const float wscale = 0.2886751345948129f;   // 1/sqrt(12)
    bs[tid] = bias[tid];
    #pragma unroll
    for (int i = 0; i < 12; ++i)
        ws[i * 256 + tid] = w[i * 256 + tid] * wscale;   // note: filled flat
    // (ws filled as flat [3072]; index i*256+tid covers all, layout ws[oo*12+c])
    // -- careful: we want ws[oo*12+c] = w[oo*12+c]*s; flat fill does exactly that.

    const int q   = tid & 31;                 // v = 4q .. 4q+3
    const int ur  = tid >> 5;                 // 0..7
    const int u   = blockIdx.x * 8 + ur;      // 0..127
    const int b   = blockIdx.y;               // 0..31

    const float F[2][2][4] = {
        { { 1.f,  7.f,  7.f,  1.f}, {-1.f, -1.f, 1.f,  1.f} },  // analysis L
        { { 1.f,  5.f, -5.f, -1.f}, {-1.f,  1.f, 1.f, -1.f} }   // analysis H
    };

    const int r0    = 2 * u - 1;
    const int cbase = 8 * q;                  // cols cbase-1 .. cbase+8

    float tv[12][4];                          // t values, kept for the conv

    #pragma unroll
    for (int ch = 0; ch < 3; ++ch) {
        float acc[4][4];                      // [kind ll,lh,hl,hh][px]
        #pragma unroll
        for (int k = 0; k < 4; ++k)
            #pragma unroll
            for (int p = 0; p < 4; ++p) acc[k][p] = 0.f;

        #pragma unroll
        for (int g = 0; g < 4; ++g) {         // input groups: ll,-lh,-hl,hh
            const int gr = g & 1, gc = g >> 1;
            const float* xp = x + ((size_t)(b * 12 + g * 3 + ch)) * HW_X;
            #pragma unroll
            for (int dy = 0; dy < 4; ++dy) {
                const int r = r0 + dy;
                float c[10];
                if (r >= 0 && r < 256) {
                    const float* rp = xp + (r << 8) + cbase;
                    const float4 A = *reinterpret_cast<const float4*>(rp);
                    const float4 B = *reinterpret_cast<const float4*>(rp + 4);
                    c[1] = A.x; c[2] = A.y; c[3] = A.z; c[4] = A.w;
                    c[5] = B.x; c[6] = B.y; c[7] = B.z; c[8] = B.w;
                    float left = 0.f, right = 0.f;
                    if (q > 0)  left  = rp[-1];
                    if (q < 31) right = rp[8];
                    c[0] = left; c[9] = right;
                } else {
                    #pragma unroll
                    for (int i = 0; i < 10; ++i) c[i] = 0.f;
                }
                #pragma unroll
                for (int p = 0; p < 4; ++p) {
                    float s0 = 0.f, s1 = 0.f;
                    #pragma unroll
                    for (int dx = 0; dx < 4; ++dx) {
                        s0 = fmaf(F[0][gc][dx], c[2 * p + dx], s0);
                        s1 = fmaf(F[1][gc][dx], c[2 * p + dx], s1);
                    }
                    acc[0][p] = fmaf(F[0][gr][dy], s0, acc[0][p]);
                    acc[1][p] = fmaf(F[1][gr][dy], s0, acc[1][p]);
                    acc[2][p] = fmaf(F[0][gr][dy], s1, acc[2][p]);
                    acc[3][p] = fmaf(F[1][gr][dy], s1, acc[3][p]);
                }
            }
        }

        const float sc = 1.f / 256.f;
        #pragma unroll
        for (int k = 0; k < 4; ++k) {
            f4v o;
            o.x = acc[k][0] * sc; o.y = acc[k][1] * sc;
            o.z = acc[k][2] * sc; o.w = acc[k][3] * sc;
            tv[k * 3 + ch][0] = o.x; tv[k * 3 + ch][1] = o.y;
            tv[k * 3 + ch][2] = o.z; tv[k * 3 + ch][3] = o.w;
            __builtin_nontemporal_store(o, reinterpret_cast<f4v*>(
                t + ((size_t)(b * 12 + k * 3 + ch)) * HW_T + (u << 7) + 4 * q));
        }
    }

    __syncthreads();   // ws/bs ready

    // ---- 1x1 conv: 256 output channels from the 12 register-resident t's
    const float SQ2 = 1.4142135623730951f;
    const int base = (u << 7) + 4 * q;
    float* outp = out + ((size_t)b * 256) * HW_T + base;

    #pragma unroll 2
    for (int oo = 0; oo < 256; ++oo) {
        const float4 w0 = *reinterpret_cast<const float4*>(&ws[oo * 12 + 0]);
        const float4 w1 = *reinterpret_cast<const float4*>(&ws[oo * 12 + 4]);
        const float4 w2 = *reinterpret_cast<const float4*>(&ws[oo * 12 + 8]);
        const float bo = bs[oo];
        float a0 = bo, a1 = bo, a2 = bo, a3 = bo;
        #pragma unroll
        for (int c = 0; c < 4; ++c) {
            const float wv = (&w0.x)[c];
            a0 = fmaf(tv[c][0], wv, a0); a1 = fmaf(tv[c][1], wv, a1);
            a2 = fmaf(tv[c][2], wv, a2); a3 = fmaf(tv[c][3], wv, a3);
        }
        #pragma unroll
        for (int c = 0; c < 4; ++c) {
            const float wv = (&w1.x)[c];
            a0 = fmaf(tv[c + 4][0], wv, a0); a1 = fmaf(tv[c + 4][1], wv, a1);
            a2 = fmaf(tv[c + 4][2], wv, a2); a3 = fmaf(tv[c + 4][3], wv, a3);
        }
        #pragma unroll
        for (int c = 0; c < 4; ++c) {
            const float wv = (&w2.x)[c];
            a0 = fmaf(tv[c + 8][0], wv, a0); a1 = fmaf(tv[c + 8][1], wv, a1);
            a2 = fmaf(tv[c + 8][2], wv, a2); a3 = fmaf(tv[c + 8][3], wv, a3);
        }
        f4v av;
        av.x = fmaxf(a0, 0.2f * a0) * SQ2;
        av.y = fmaxf(a1, 0.2f * a1) * SQ2;
        av.z = fmaxf(a2, 0.2f * a2) * SQ2;
        av.w = fmaxf(a3, 0.2f * a3) * SQ2;
        __builtin_nontemporal_store(
            av, reinterpret_cast<f4v*>(outp + (size_t)oo * HW_T));
    }
}

extern "C" void kernel_launch(void* const* d_in, const int* in_sizes, int n_in,
                              void* d_out, int out_size, void* d_ws, size_t ws_size,
                              hipStream_t stream) {
    const float* x    = (const float*)d_in[0];
    const float* wgt  = (const float*)d_in[1];
    const float* bias = (const float*)d_in[2];
    float* t   = (float*)d_out;
    float* out = t + T_ELEMS;

    dim3 blk(256, 1, 1), grd(16, 32, 1);
    hipLaunchKernelGGL(fused_fromrgb_kernel, grd, blk, 0, stream,
                       x, wgt, bias, t, out);
}

// Round 4
// 130.111 us; speedup vs baseline: 2.0095x; 1.0201x over previous
//
#include <hip/hip_runtime.h>

// Shapes (fixed): x (32,12,256,256) f32, weight (256,12,1,1) f32, bias (256) f32
// Outputs: t (32,12,128,128) then out (32,256,128,128), concatenated in d_out.

#define T_ELEMS 6291456      // 32*12*128*128
#define HW_T    16384        // 128*128
#define HW_X    65536        // 256*256

typedef float f2v __attribute__((ext_vector_type(2)));

// Fully fused: iwt(up2)->blur(down2)->dwt(down2) as one separable stride-2
// 4x4-tap filter bank (t kept in registers, nt-stored), then 12->256 1x1
// conv + bias + lrelu*sqrt2 directly from registers.
// 2 px/thread: block = 256 threads = 4 waves = 4 u-rows (64 lanes x 2 px).
// Grid (32, 32) = 1024 blocks -> 4096 waves -> 16 waves/CU.
__global__ __launch_bounds__(256) void fused_fromrgb_kernel(
    const float* __restrict__ x, const float* __restrict__ w,
    const float* __restrict__ bias, float* __restrict__ t,
    float* __restrict__ out)
{
    __shared__ float ws[256 * 12];
    __shared__ float bs[256];
    const int tid = threadIdx.x;

    // Stage weights (overlaps with phase 1; sync deferred until conv).
    const float wscale = 0.2886751345948129f;   // 1/sqrt(12)
    bs[tid] = bias[tid];
    #pragma unroll
    for (int i = 0; i < 12; ++i)
        ws[i * 256 + tid] = w[i * 256 + tid] * wscale;  // flat fill of ws[oo*12+c]

    const int l  = tid & 63;                  // lane: v = 2l, 2l+1
    const int ur = tid >> 6;                  // 0..3
    const int u  = blockIdx.x * 4 + ur;       // 0..127
    const int b  = blockIdx.y;                // 0..31

    const float F[2][2][4] = {
        { { 1.f,  7.f,  7.f,  1.f}, {-1.f, -1.f, 1.f,  1.f} },  // analysis L
        { { 1.f,  5.f, -5.f, -1.f}, {-1.f,  1.f, 1.f, -1.f} }   // analysis H
    };

    const int r0    = 2 * u - 1;
    const int cbase = 4 * l;                  // cols cbase-1 .. cbase+4

    float tv[12][2];                          // t values, kept for the conv

    #pragma unroll
    for (int ch = 0; ch < 3; ++ch) {
        float acc[4][2];                      // [kind ll,lh,hl,hh][px]
        #pragma unroll
        for (int k = 0; k < 4; ++k) { acc[k][0] = 0.f; acc[k][1] = 0.f; }

        #pragma unroll
        for (int g = 0; g < 4; ++g) {         // input groups: ll,-lh,-hl,hh
            const int gr = g & 1, gc = g >> 1;
            const float* xp = x + ((size_t)(b * 12 + g * 3 + ch)) * HW_X;
            #pragma unroll
            for (int dy = 0; dy < 4; ++dy) {
                const int r = r0 + dy;
                float c[6];
                if (r >= 0 && r < 256) {
                    const float* rp = xp + (r << 8) + cbase;
                    const float4 A = *reinterpret_cast<const float4*>(rp);
                    c[1] = A.x; c[2] = A.y; c[3] = A.z; c[4] = A.w;
                    c[0] = (l > 0)  ? rp[-1] : 0.f;
                    c[5] = (l < 63) ? rp[4]  : 0.f;
                } else {
                    #pragma unroll
                    for (int i = 0; i < 6; ++i) c[i] = 0.f;
                }
                #pragma unroll
                for (int p = 0; p < 2; ++p) {
                    float s0 = 0.f, s1 = 0.f;
                    #pragma unroll
                    for (int dx = 0; dx < 4; ++dx) {
                        s0 = fmaf(F[0][gc][dx], c[2 * p + dx], s0);
                        s1 = fmaf(F[1][gc][dx], c[2 * p + dx], s1);
                    }
                    acc[0][p] = fmaf(F[0][gr][dy], s0, acc[0][p]);
                    acc[1][p] = fmaf(F[1][gr][dy], s0, acc[1][p]);
                    acc[2][p] = fmaf(F[0][gr][dy], s1, acc[2][p]);
                    acc[3][p] = fmaf(F[1][gr][dy], s1, acc[3][p]);
                }
            }
        }

        const float sc = 1.f / 256.f;
        #pragma unroll
        for (int k = 0; k < 4; ++k) {
            f2v o;
            o.x = acc[k][0] * sc; o.y = acc[k][1] * sc;
            tv[k * 3 + ch][0] = o.x; tv[k * 3 + ch][1] = o.y;
            __builtin_nontemporal_store(o, reinterpret_cast<f2v*>(
                t + ((size_t)(b * 12 + k * 3 + ch)) * HW_T + (u << 7) + 2 * l));
        }
    }

    __syncthreads();   // ws/bs ready

    // ---- 1x1 conv: 256 output channels from the 12 register-resident t's
    const float SQ2 = 1.4142135623730951f;
    const int base = (u << 7) + 2 * l;
    float* outp = out + ((size_t)b * 256) * HW_T + base;

    #pragma unroll 4
    for (int oo = 0; oo < 256; ++oo) {
        const float4 w0 = *reinterpret_cast<const float4*>(&ws[oo * 12 + 0]);
        const float4 w1 = *reinterpret_cast<const float4*>(&ws[oo * 12 + 4]);
        const float4 w2 = *reinterpret_cast<const float4*>(&ws[oo * 12 + 8]);
        const float bo = bs[oo];
        float a0 = bo, a1 = bo;
        #pragma unroll
        for (int c = 0; c < 4; ++c) {
            const float wv = (&w0.x)[c];
            a0 = fmaf(tv[c][0], wv, a0); a1 = fmaf(tv[c][1], wv, a1);
        }
        #pragma unroll
        for (int c = 0; c < 4; ++c) {
            const float wv = (&w1.x)[c];
            a0 = fmaf(tv[c + 4][0], wv, a0); a1 = fmaf(tv[c + 4][1], wv, a1);
        }
        #pragma unroll
        for (int c = 0; c < 4; ++c) {
            const float wv = (&w2.x)[c];
            a0 = fmaf(tv[c + 8][0], wv, a0); a1 = fmaf(tv[c + 8][1], wv, a1);
        }
        f2v av;
        av.x = fmaxf(a0, 0.2f * a0) * SQ2;
        av.y = fmaxf(a1, 0.2f * a1) * SQ2;
        __builtin_nontemporal_store(
            av, reinterpret_cast<f2v*>(outp + (size_t)oo * HW_T));
    }
}

extern "C" void kernel_launch(void* const* d_in, const int* in_sizes, int n_in,
                              void* d_out, int out_size, void* d_ws, size_t ws_size,
                              hipStream_t stream) {
    const float* x    = (const float*)d_in[0];
    const float* wgt  = (const float*)d_in[1];
    const float* bias = (const float*)d_in[2];
    float* t   = (float*)d_out;
    float* out = t + T_ELEMS;

    dim3 blk(256, 1, 1), grd(32, 32, 1);
    hipLaunchKernelGGL(fused_fromrgb_kernel, grd, blk, 0, stream,
                       x, wgt, bias, t, out);
}